// Round 6
// baseline (205.035 us; speedup 1.0000x reference)
//
#include <hip/hip_runtime.h>

typedef _Float16 half8 __attribute__((ext_vector_type(8)));
typedef _Float16 half4_t __attribute__((ext_vector_type(4)));
typedef float f32x4 __attribute__((ext_vector_type(4)));

#define GK 1024
#define MEG (1024 * 1024)
#define LOG2E 1.44269504088896f

// async global->LDS, 16B per lane; lptr wave-uniform, lane i's data lands at lptr + i*16
#define GLD16(gptr, lptr) \
    __builtin_amdgcn_global_load_lds((const __attribute__((address_space(1))) void*)(gptr), \
                                     (__attribute__((address_space(3))) void*)(lptr), 16, 0, 0)

// ---------------- fp32 -> fp16 convert (all 5 tensors, one launch) ----------------
__global__ void cvt_all_kernel(const float* __restrict__ hidden,
                               const float* __restrict__ Wq,
                               const float* __restrict__ Wk,
                               const float* __restrict__ Wv,
                               const float* __restrict__ Wo,
                               _Float16* __restrict__ ws) {
    int b = blockIdx.x;
    const float* src;
    _Float16* dst;
    if (b < 4096)      { src = hidden; dst = ws; }
    else if (b < 5120) { src = Wq; dst = ws + 4 * MEG; b -= 4096; }
    else if (b < 6144) { src = Wk; dst = ws + 5 * MEG; b -= 5120; }
    else if (b < 7168) { src = Wv; dst = ws + 6 * MEG; b -= 6144; }
    else               { src = Wo; dst = ws + 7 * MEG; b -= 7168; }
    int i = (b * 256 + threadIdx.x) * 4;
    f32x4 v = *(const f32x4*)(src + i);
    half4_t h;
    h[0] = (_Float16)v[0]; h[1] = (_Float16)v[1];
    h[2] = (_Float16)v[2]; h[3] = (_Float16)v[3];
    *(half4_t*)(dst + i) = h;
}

// ---------------- QKV GEMM: C[4096,1024] = A @ B^T, z picks (Wq,Q)/(Wk,K)/(Wv,V) ----------------
__global__ __launch_bounds__(256) void gemm_qkv_kernel(
    const _Float16* __restrict__ A,
    const _Float16* __restrict__ B0,
    const _Float16* __restrict__ B1,
    const _Float16* __restrict__ B2,
    _Float16* __restrict__ O0,
    _Float16* __restrict__ O1,
    _Float16* __restrict__ O2)
{
    int z = blockIdx.z;
    const _Float16* Bw = (z == 0) ? B0 : ((z == 1) ? B1 : B2);
    _Float16* Oh = (z == 0) ? O0 : ((z == 1) ? O1 : O2);

    __shared__ __attribute__((aligned(16))) _Float16 sA[2][128][32];
    __shared__ __attribute__((aligned(16))) _Float16 sB[2][128][32];

    const int tid = threadIdx.x;
    const int wave = tid >> 6, lane = tid & 63;
    const int quad = lane >> 4, l16 = lane & 15;
    const int wr = wave >> 1, wc = wave & 1;
    const int M0 = blockIdx.y * 128, N0 = blockIdx.x * 128;

    const int rl = lane >> 2;
    const int cl = (lane & 3) * 8;   // halfs within chunk
    const size_t aRow0 = (size_t)(M0 + wave * 16 + rl) * GK + cl;
    const size_t aRow1 = aRow0 + (size_t)64 * GK;
    const size_t bRow0 = (size_t)(N0 + wave * 16 + rl) * GK + cl;
    const size_t bRow1 = bRow0 + (size_t)64 * GK;
    _Float16* ldsA[2][2] = {{&sA[0][wave * 16][0], &sA[0][64 + wave * 16][0]},
                            {&sA[1][wave * 16][0], &sA[1][64 + wave * 16][0]}};
    _Float16* ldsB[2][2] = {{&sB[0][wave * 16][0], &sB[0][64 + wave * 16][0]},
                            {&sB[1][wave * 16][0], &sB[1][64 + wave * 16][0]}};

    f32x4 acc[4][4] = {};

    for (int kt = 0; kt < GK / 64; ++kt) {
        const int ko = kt * 64;
        #pragma unroll
        for (int c = 0; c < 2; ++c) {
            GLD16(A + aRow0 + ko + c * 32, ldsA[c][0]);
            GLD16(A + aRow1 + ko + c * 32, ldsA[c][1]);
            GLD16(Bw + bRow0 + ko + c * 32, ldsB[c][0]);
            GLD16(Bw + bRow1 + ko + c * 32, ldsB[c][1]);
        }
        __syncthreads();
        #pragma unroll
        for (int c = 0; c < 2; ++c) {
            half8 af[4], bf[4];
            #pragma unroll
            for (int i = 0; i < 4; ++i)
                af[i] = *(const half8*)&sA[c][wr * 64 + i * 16 + l16][quad * 8];
            #pragma unroll
            for (int j = 0; j < 4; ++j)
                bf[j] = *(const half8*)&sB[c][wc * 64 + j * 16 + l16][quad * 8];
            #pragma unroll
            for (int i = 0; i < 4; ++i)
                #pragma unroll
                for (int j = 0; j < 4; ++j)
                    acc[i][j] = __builtin_amdgcn_mfma_f32_16x16x32_f16(af[i], bf[j], acc[i][j], 0, 0, 0);
        }
        __syncthreads();
    }

    #pragma unroll
    for (int i = 0; i < 4; ++i) {
        #pragma unroll
        for (int j = 0; j < 4; ++j) {
            #pragma unroll
            for (int r = 0; r < 4; ++r) {
                int m = M0 + wr * 64 + i * 16 + quad * 4 + r;
                int n = N0 + wc * 64 + j * 16 + l16;
                int b = m >> 10, s = m & 1023, hh = n >> 6, d = n & 63;
                Oh[((size_t)((b * 16 + hh) * 1024 + s)) * 64 + d] = (_Float16)acc[i][j][r];
            }
        }
    }
}

// ---------------- Output GEMM: C[4096,1024] fp32 = A @ B^T ----------------
__global__ __launch_bounds__(256) void gemm_o_kernel(
    const _Float16* __restrict__ A,
    const _Float16* __restrict__ Bw,
    float* __restrict__ Of)
{
    __shared__ __attribute__((aligned(16))) _Float16 sA[2][64][32];
    __shared__ __attribute__((aligned(16))) _Float16 sB[2][128][32];

    const int tid = threadIdx.x;
    const int wave = tid >> 6, lane = tid & 63;
    const int quad = lane >> 4, l16 = lane & 15;
    const int M0 = blockIdx.y * 64, N0 = blockIdx.x * 128;

    const int rl = lane >> 2;
    const int cl = (lane & 3) * 8;
    const size_t aRow  = (size_t)(M0 + wave * 16 + rl) * GK + cl;
    const size_t bRow0 = (size_t)(N0 + wave * 16 + rl) * GK + cl;
    const size_t bRow1 = bRow0 + (size_t)64 * GK;
    _Float16* ldsA[2]    = {&sA[0][wave * 16][0], &sA[1][wave * 16][0]};
    _Float16* ldsB[2][2] = {{&sB[0][wave * 16][0], &sB[0][64 + wave * 16][0]},
                            {&sB[1][wave * 16][0], &sB[1][64 + wave * 16][0]}};

    f32x4 acc[4][2] = {};

    for (int kt = 0; kt < GK / 64; ++kt) {
        const int ko = kt * 64;
        #pragma unroll
        for (int c = 0; c < 2; ++c) {
            GLD16(A + aRow + ko + c * 32, ldsA[c]);
            GLD16(Bw + bRow0 + ko + c * 32, ldsB[c][0]);
            GLD16(Bw + bRow1 + ko + c * 32, ldsB[c][1]);
        }
        __syncthreads();
        #pragma unroll
        for (int c = 0; c < 2; ++c) {
            half8 af[4], bf[2];
            #pragma unroll
            for (int i = 0; i < 4; ++i)
                af[i] = *(const half8*)&sA[c][i * 16 + l16][quad * 8];
            #pragma unroll
            for (int j = 0; j < 2; ++j)
                bf[j] = *(const half8*)&sB[c][wave * 32 + j * 16 + l16][quad * 8];
            #pragma unroll
            for (int i = 0; i < 4; ++i)
                #pragma unroll
                for (int j = 0; j < 2; ++j)
                    acc[i][j] = __builtin_amdgcn_mfma_f32_16x16x32_f16(af[i], bf[j], acc[i][j], 0, 0, 0);
        }
        __syncthreads();
    }

    #pragma unroll
    for (int i = 0; i < 4; ++i) {
        #pragma unroll
        for (int j = 0; j < 2; ++j) {
            #pragma unroll
            for (int r = 0; r < 4; ++r) {
                int m = M0 + i * 16 + quad * 4 + r;
                int n = N0 + wave * 32 + j * 16 + l16;
                Of[(size_t)m * 1024 + n] = acc[i][j][r];
            }
        }
    }
}

// ---------------- V transpose: [BH][S][64] -> [BH][64][S] (fp16), half8 IO ----------------
__global__ __launch_bounds__(256) void transpose_v_kernel(
    const _Float16* __restrict__ V, _Float16* __restrict__ VT) {
    __shared__ __attribute__((aligned(16))) _Float16 sT[64][72];   // [d][s_local], padded
    const int s0 = blockIdx.x * 64;
    const int bh = blockIdx.y;
    const _Float16* Vb = V + (size_t)bh * 1024 * 64 + (size_t)s0 * 64;
    _Float16* Tb = VT + (size_t)bh * 64 * 1024 + s0;
    const int r = threadIdx.x >> 3;        // 0..31
    const int c8 = (threadIdx.x & 7) * 8;  // 0..56
    #pragma unroll
    for (int p = 0; p < 2; ++p) {
        const int row = p * 32 + r;                         // s_local
        half8 v = *(const half8*)(Vb + (size_t)row * 64 + c8);
        #pragma unroll
        for (int e = 0; e < 8; ++e) sT[c8 + e][row] = v[e]; // transpose scatter
    }
    __syncthreads();
    #pragma unroll
    for (int p = 0; p < 2; ++p) {
        const int d = p * 32 + r;
        half8 o = *(const half8*)&sT[d][c8];
        *(half8*)(Tb + (size_t)d * 1024 + c8) = o;
    }
}

// ---------------- flash attention, TRANSPOSED scores (K·Q^T), QBLK=128 ----------------
// R6: q-block 64->128. Each wave owns 32 q-rows (two 16-row groups g=0,1). kf/vf
// LDS fragments are read ONCE per kv-tile and feed both g-groups' MFMAs -> LDS
// reads per unit work -44%, staging bytes & barriers per unit work halve, MFMA
// per staging doubles. Grid 512 = exactly 2 blocks/CU; LDS 57.6KB. Softmax state
// (m,l,acc) per g; g-chains independent (ILP). Bias window 1151; uniform-tile
// condition re-derived for 128-row span: kt<=2qt-3 || kt>=2qt+4 (min |delta|=129>=91).
__global__ __launch_bounds__(256) void attn_kernel(
    const _Float16* __restrict__ Q,
    const _Float16* __restrict__ K,
    const _Float16* __restrict__ VT,
    const float* __restrict__ rel_bias,   // [32][16]
    _Float16* __restrict__ ctx)           // [B*S, 1024]
{
    const int S = 1024;
    const int qt = blockIdx.x;            // 0..7, QBLK=128
    const int q0 = qt * 128;
    const int h = blockIdx.y;
    const int b = blockIdx.z;
    const int bh = b * 16 + h;
    const _Float16* Qh = Q + (size_t)bh * S * 64;
    const _Float16* Kh = K + (size_t)bh * S * 64;
    const _Float16* VTh = VT + (size_t)bh * 64 * S;

    __shared__ __attribute__((aligned(16))) _Float16 sQ[128][72];
    __shared__ __attribute__((aligned(16))) _Float16 sK[64][72];
    __shared__ __attribute__((aligned(16))) _Float16 sVt[64][72];      // [d][kpos]
    __shared__ __attribute__((aligned(16))) _Float16 sP[4][2][16][72]; // [wave][g][q=l16][kpos]
    __shared__ _Float16 sBias[1152];

    const int tid = threadIdx.x;
    const int wave = tid >> 6, lane = tid & 63;
    const int quad = lane >> 4, l16 = lane & 15;

    {   // stage Q tile (once): 4 rows per thread
        int r = tid >> 3, c = (tid & 7) * 8;
        #pragma unroll
        for (int p = 0; p < 4; ++p)
            *(half8*)&sQ[r + p * 32][c] =
                *(const half8*)(Qh + (size_t)(q0 + r + p * 32) * 64 + c);
    }
    // bias window: idx = kpos - q + q0 + 127 in [0,1150]
    for (int i = tid; i < 1151; i += 256) {
        int delta = i - (q0 + 127);            // kpos - q
        int rb = (delta > 0) ? 16 : 0;
        int n = (delta < 0) ? -delta : delta;
        int bucket;
        if (n < 8) bucket = rb + n;
        else bucket = rb + 8 + (n >= 12) + (n >= 16) + (n >= 23) + (n >= 32)
                             + (n >= 46) + (n >= 64) + (n >= 91);
        sBias[i] = (_Float16)rel_bias[bucket * 16 + h];
    }
    __syncthreads();

    // q-fragments: wave's 32 q-rows, two groups of 16 (B-operand; lane l16 = q in group)
    half8 qf[2][2];
    #pragma unroll
    for (int g = 0; g < 2; ++g) {
        qf[g][0] = *(const half8*)&sQ[wave * 32 + g * 16 + l16][quad * 8];
        qf[g][1] = *(const half8*)&sQ[wave * 32 + g * 16 + l16][32 + quad * 8];
    }

    // staging pointers (advance by constant stride per kt)
    const int sr = tid >> 3;            // 0..31
    const int sc_ = (tid & 7) * 8;      // 0..56
    const _Float16* kp0 = Kh + (size_t)sr * 64 + sc_;          // += 4096 per kt
    const _Float16* kp1 = kp0 + (size_t)32 * 64;
    const _Float16* vp0 = VTh + (size_t)sr * S + sc_;          // += 64 per kt
    const _Float16* vp1 = vp0 + (size_t)32 * S;
    _Float16* sKw0 = &sK[sr][sc_];
    _Float16* sKw1 = &sK[sr + 32][sc_];
    _Float16* sVw0 = &sVt[sr][sc_];
    _Float16* sVw1 = &sVt[sr + 32][sc_];

    // preload tile kt=0 into registers
    half8 rk0 = *(const half8*)kp0;
    half8 rk1 = *(const half8*)kp1;
    half8 rv0 = *(const half8*)vp0;
    half8 rv1 = *(const half8*)vp1;
    kp0 += 4096; kp1 += 4096; vp0 += 64; vp1 += 64;

    float m_run[2] = {-INFINITY, -INFINITY};
    float l_run[2] = {0.0f, 0.0f};
    f32x4 acc[2][4] = {};   // acc[g][dt][r] = out^T[d = dt*16+quad*4+r][q = l16 of group g]

    for (int kt = 0; kt < 16; ++kt) {
        __syncthreads();   // prior iter's sK/sVt reads done
        *(half8*)sKw0 = rk0;
        *(half8*)sKw1 = rk1;
        *(half8*)sVw0 = rv0;
        *(half8*)sVw1 = rv1;
        __syncthreads();   // tile visible to all waves
        if (kt < 15) {     // prefetch next tile; latency hidden by compute below
            rk0 = *(const half8*)kp0;
            rk1 = *(const half8*)kp1;
            rv0 = *(const half8*)vp0;
            rv1 = *(const half8*)vp1;
            kp0 += 4096; kp1 += 4096; vp0 += 64; vp1 += 64;
        }

        // K/V fragments: read ONCE, consumed by both q-groups
        half8 kf[8], vf[8];
        #pragma unroll
        for (int j = 0; j < 4; ++j) {
            kf[j * 2]     = *(const half8*)&sK[j * 16 + l16][quad * 8];
            kf[j * 2 + 1] = *(const half8*)&sK[j * 16 + l16][32 + quad * 8];
        }
        #pragma unroll
        for (int dt = 0; dt < 4; ++dt) {
            vf[dt * 2]     = *(const half8*)&sVt[dt * 16 + l16][quad * 8];
            vf[dt * 2 + 1] = *(const half8*)&sVt[dt * 16 + l16][32 + quad * 8];
        }

        const bool uni = (kt <= 2 * qt - 3) || (kt >= 2 * qt + 4);

        #pragma unroll
        for (int g = 0; g < 2; ++g) {
            // scores transposed: sc[j][r] = S[kpos = kt*64 + j*16 + quad*4 + r][q]
            f32x4 sc[4] = {};
            #pragma unroll
            for (int j = 0; j < 4; ++j) {
                sc[j] = __builtin_amdgcn_mfma_f32_16x16x32_f16(kf[j * 2], qf[g][0], sc[j], 0, 0, 0);
                sc[j] = __builtin_amdgcn_mfma_f32_16x16x32_f16(kf[j * 2 + 1], qf[g][1], sc[j], 0, 0, 0);
            }

            const int bbase = kt * 64 + quad * 4 - wave * 32 - g * 16 - l16 + 127;
            float ps = 0.0f;
            if (uni) {
                // uniform tile: one bucket -> bias lane-uniform; fold bias & max into exp2 arg
                const float cb = (float)sBias[bbase];
                float mx = fmaxf(fmaxf(fmaxf(sc[0][0], sc[0][1]), fmaxf(sc[0][2], sc[0][3])),
                                 fmaxf(fmaxf(sc[1][0], sc[1][1]), fmaxf(sc[1][2], sc[1][3])));
                mx = fmaxf(mx, fmaxf(fmaxf(fmaxf(sc[2][0], sc[2][1]), fmaxf(sc[2][2], sc[2][3])),
                                     fmaxf(fmaxf(sc[3][0], sc[3][1]), fmaxf(sc[3][2], sc[3][3]))));
                mx = fmaxf(mx, __shfl_xor(mx, 16));
                mx = fmaxf(mx, __shfl_xor(mx, 32));
                float mnew = fmaxf(m_run[g], mx + cb);
                float alpha = __expf(m_run[g] - mnew);
                m_run[g] = mnew;
                const float kk = (cb - mnew) * LOG2E;
                #pragma unroll
                for (int j = 0; j < 4; ++j) {
                    half4_t pw;
                    #pragma unroll
                    for (int r = 0; r < 4; ++r) {
                        float p = __builtin_exp2f(__builtin_fmaf(sc[j][r], LOG2E, kk));
                        ps += p;
                        pw[r] = (_Float16)p;
                    }
                    *(half4_t*)&sP[wave][g][l16][j * 16 + quad * 4] = pw;
                }
                l_run[g] = l_run[g] * alpha + ps;
                #pragma unroll
                for (int dt = 0; dt < 4; ++dt) acc[g][dt] *= alpha;
            } else {
                // mixed tile: per-element bias (exact path)
                #pragma unroll
                for (int j = 0; j < 4; ++j)
                    #pragma unroll
                    for (int r = 0; r < 4; ++r)
                        sc[j][r] += (float)sBias[bbase + j * 16 + r];
                float mx = fmaxf(fmaxf(fmaxf(sc[0][0], sc[0][1]), fmaxf(sc[0][2], sc[0][3])),
                                 fmaxf(fmaxf(sc[1][0], sc[1][1]), fmaxf(sc[1][2], sc[1][3])));
                mx = fmaxf(mx, fmaxf(fmaxf(fmaxf(sc[2][0], sc[2][1]), fmaxf(sc[2][2], sc[2][3])),
                                     fmaxf(fmaxf(sc[3][0], sc[3][1]), fmaxf(sc[3][2], sc[3][3]))));
                mx = fmaxf(mx, __shfl_xor(mx, 16));
                mx = fmaxf(mx, __shfl_xor(mx, 32));
                float mnew = fmaxf(m_run[g], mx);
                float alpha = __expf(m_run[g] - mnew);
                m_run[g] = mnew;
                #pragma unroll
                for (int j = 0; j < 4; ++j) {
                    half4_t pw;
                    #pragma unroll
                    for (int r = 0; r < 4; ++r) {
                        float p = __expf(sc[j][r] - mnew);
                        ps += p;
                        pw[r] = (_Float16)p;
                    }
                    *(half4_t*)&sP[wave][g][l16][j * 16 + quad * 4] = pw;
                }
                l_run[g] = l_run[g] * alpha + ps;
                #pragma unroll
                for (int dt = 0; dt < 4; ++dt) acc[g][dt] *= alpha;
            }
            // NO barrier: sP slice is wave-private; same-wave ds_write -> ds_read is ordered.

            half8 pf0 = *(const half8*)&sP[wave][g][l16][quad * 8];        // kpos 0..31
            half8 pf1 = *(const half8*)&sP[wave][g][l16][32 + quad * 8];   // kpos 32..63
            #pragma unroll
            for (int dt = 0; dt < 4; ++dt) {
                acc[g][dt] = __builtin_amdgcn_mfma_f32_16x16x32_f16(vf[dt * 2], pf0, acc[g][dt], 0, 0, 0);
                acc[g][dt] = __builtin_amdgcn_mfma_f32_16x16x32_f16(vf[dt * 2 + 1], pf1, acc[g][dt], 0, 0, 0);
            }
        }
    }

    // final: reduce row-sum across quads, normalize, store half4 chunks
    #pragma unroll
    for (int g = 0; g < 2; ++g) {
        float l = l_run[g];
        l += __shfl_xor(l, 16);
        l += __shfl_xor(l, 32);
        const float inv = 1.0f / l;
        const size_t qg = (size_t)(b * 1024 + q0 + wave * 32 + g * 16 + l16);
        #pragma unroll
        for (int dt = 0; dt < 4; ++dt) {
            half4_t o;
            #pragma unroll
            for (int r = 0; r < 4; ++r) o[r] = (_Float16)(acc[g][dt][r] * inv);
            *(half4_t*)&ctx[qg * 1024 + h * 64 + dt * 16 + quad * 4] = o;
        }
    }
}

// ---------------- launch ----------------
extern "C" void kernel_launch(void* const* d_in, const int* in_sizes, int n_in,
                              void* d_out, int out_size, void* d_ws, size_t ws_size,
                              hipStream_t stream) {
    const float* hidden   = (const float*)d_in[0];
    const float* Wq       = (const float*)d_in[1];
    const float* Wk       = (const float*)d_in[2];
    const float* Wv       = (const float*)d_in[3];
    const float* Wo       = (const float*)d_in[4];
    const float* rel_bias = (const float*)d_in[5];
    float* out = (float*)d_out;

    _Float16* ws    = (_Float16*)d_ws;
    _Float16* h16   = ws;                     // 4M halves (reused as VT after gemm_qkv)
    _Float16* wq16  = ws + 4 * (size_t)MEG;
    _Float16* wk16  = ws + 5 * (size_t)MEG;
    _Float16* wv16  = ws + 6 * (size_t)MEG;
    _Float16* wo16  = ws + 7 * (size_t)MEG;
    _Float16* Qs    = ws + 8 * (size_t)MEG;   // [B,H,S,64]
    _Float16* Ks    = ws + 12 * (size_t)MEG;
    _Float16* Vs    = ws + 16 * (size_t)MEG;
    _Float16* ctx16 = ws + 20 * (size_t)MEG;  // [B*S,1024]
    _Float16* VTs   = h16;                    // V^T [B,H,64,S] — h16 dead after gemm_qkv

    cvt_all_kernel<<<8192, 256, 0, stream>>>(hidden, Wq, Wk, Wv, Wo, ws);

    gemm_qkv_kernel<<<dim3(8, 32, 3), 256, 0, stream>>>(
        h16, wq16, wk16, wv16, Qs, Ks, Vs);

    transpose_v_kernel<<<dim3(16, 64), 256, 0, stream>>>(Vs, VTs);

    // QBLK=128: 8 q-tiles x 16 heads x 4 batch = 512 blocks = 2/CU
    attn_kernel<<<dim3(8, 16, 4), 256, 0, stream>>>(Qs, Ks, VTs, rel_bias, ctx16);

    gemm_o_kernel<<<dim3(8, 64), 256, 0, stream>>>(ctx16, wo16, out);
}

// Round 8
// 191.630 us; speedup vs baseline: 1.0700x; 1.0700x over previous
//
#include <hip/hip_runtime.h>

typedef _Float16 half8 __attribute__((ext_vector_type(8)));
typedef _Float16 half4_t __attribute__((ext_vector_type(4)));
typedef float f32x4 __attribute__((ext_vector_type(4)));

#define GK 1024
#define MEG (1024 * 1024)
#define LOG2E 1.44269504088896f

// async global->LDS, 16B per lane; lptr wave-uniform, lane i's data lands at lptr + i*16
#define GLD16(gptr, lptr) \
    __builtin_amdgcn_global_load_lds((const __attribute__((address_space(1))) void*)(gptr), \
                                     (__attribute__((address_space(3))) void*)(lptr), 16, 0, 0)

// ---------------- fp32 -> fp16 convert (all 5 tensors, one launch) ----------------
__global__ void cvt_all_kernel(const float* __restrict__ hidden,
                               const float* __restrict__ Wq,
                               const float* __restrict__ Wk,
                               const float* __restrict__ Wv,
                               const float* __restrict__ Wo,
                               _Float16* __restrict__ ws) {
    int b = blockIdx.x;
    const float* src;
    _Float16* dst;
    if (b < 4096)      { src = hidden; dst = ws; }
    else if (b < 5120) { src = Wq; dst = ws + 4 * MEG; b -= 4096; }
    else if (b < 6144) { src = Wk; dst = ws + 5 * MEG; b -= 5120; }
    else if (b < 7168) { src = Wv; dst = ws + 6 * MEG; b -= 6144; }
    else               { src = Wo; dst = ws + 7 * MEG; b -= 7168; }
    int i = (b * 256 + threadIdx.x) * 4;
    f32x4 v = *(const f32x4*)(src + i);
    half4_t h;
    h[0] = (_Float16)v[0]; h[1] = (_Float16)v[1];
    h[2] = (_Float16)v[2]; h[3] = (_Float16)v[3];
    *(half4_t*)(dst + i) = h;
}

// ---------------- QKV GEMM: C[4096,1024] = A @ B^T, z picks (Wq,Q)/(Wk,K)/(Wv,V) ----------------
// R7: (1) XCD-aware 1D grid decode — all 8 N-blocks of one (M-panel, z) land on one
//     XCD, so the 512KB A-panel is fetched once per XCD instead of 8x (A=8MB > 4MB L2).
// (2) z==2 (V) writes TRANSPOSED [bh][d][s] layout directly (half4 along r: s varies
//     with r, d fixed -> natural 8B vector store). transpose_v kernel deleted.
__global__ __launch_bounds__(256) void gemm_qkv_kernel(
    const _Float16* __restrict__ A,
    const _Float16* __restrict__ B0,
    const _Float16* __restrict__ B1,
    const _Float16* __restrict__ B2,
    _Float16* __restrict__ O0,
    _Float16* __restrict__ O1,
    _Float16* __restrict__ O2)
{
    // decode: lid = xcd + 8*(xb + 8*gidx), gg = xcd*12 + gidx in [0,96), y=gg&31, z=gg>>5
    const int lid = blockIdx.x;
    const int xcd = lid & 7;
    const int rr = lid >> 3;              // 0..95
    const int xb = rr & 7;                // N-block
    const int gg = xcd * 12 + (rr >> 3);  // 0..95
    const int yb = gg & 31;               // M-block
    const int z  = gg >> 5;               // 0..2
    const _Float16* Bw = (z == 0) ? B0 : ((z == 1) ? B1 : B2);
    _Float16* Oh = (z == 0) ? O0 : ((z == 1) ? O1 : O2);

    __shared__ __attribute__((aligned(16))) _Float16 sA[2][128][32];
    __shared__ __attribute__((aligned(16))) _Float16 sB[2][128][32];

    const int tid = threadIdx.x;
    const int wave = tid >> 6, lane = tid & 63;
    const int quad = lane >> 4, l16 = lane & 15;
    const int wr = wave >> 1, wc = wave & 1;
    const int M0 = yb * 128, N0 = xb * 128;

    const int rl = lane >> 2;
    const int cl = (lane & 3) * 8;   // halfs within chunk
    const size_t aRow0 = (size_t)(M0 + wave * 16 + rl) * GK + cl;
    const size_t aRow1 = aRow0 + (size_t)64 * GK;
    const size_t bRow0 = (size_t)(N0 + wave * 16 + rl) * GK + cl;
    const size_t bRow1 = bRow0 + (size_t)64 * GK;
    _Float16* ldsA[2][2] = {{&sA[0][wave * 16][0], &sA[0][64 + wave * 16][0]},
                            {&sA[1][wave * 16][0], &sA[1][64 + wave * 16][0]}};
    _Float16* ldsB[2][2] = {{&sB[0][wave * 16][0], &sB[0][64 + wave * 16][0]},
                            {&sB[1][wave * 16][0], &sB[1][64 + wave * 16][0]}};

    f32x4 acc[4][4] = {};

    for (int kt = 0; kt < GK / 64; ++kt) {
        const int ko = kt * 64;
        #pragma unroll
        for (int c = 0; c < 2; ++c) {
            GLD16(A + aRow0 + ko + c * 32, ldsA[c][0]);
            GLD16(A + aRow1 + ko + c * 32, ldsA[c][1]);
            GLD16(Bw + bRow0 + ko + c * 32, ldsB[c][0]);
            GLD16(Bw + bRow1 + ko + c * 32, ldsB[c][1]);
        }
        __syncthreads();
        #pragma unroll
        for (int c = 0; c < 2; ++c) {
            half8 af[4], bf[4];
            #pragma unroll
            for (int i = 0; i < 4; ++i)
                af[i] = *(const half8*)&sA[c][wr * 64 + i * 16 + l16][quad * 8];
            #pragma unroll
            for (int j = 0; j < 4; ++j)
                bf[j] = *(const half8*)&sB[c][wc * 64 + j * 16 + l16][quad * 8];
            #pragma unroll
            for (int i = 0; i < 4; ++i)
                #pragma unroll
                for (int j = 0; j < 4; ++j)
                    acc[i][j] = __builtin_amdgcn_mfma_f32_16x16x32_f16(af[i], bf[j], acc[i][j], 0, 0, 0);
        }
        __syncthreads();
    }

    if (z == 2) {
        // V: store transposed [bh][d][s] (VT). Along r, s varies by 1 -> half4 store.
        #pragma unroll
        for (int i = 0; i < 4; ++i) {
            #pragma unroll
            for (int j = 0; j < 4; ++j) {
                int m = M0 + wr * 64 + i * 16 + quad * 4;        // r=0 base (s-dim)
                int n = N0 + wc * 64 + j * 16 + l16;
                int b = m >> 10, s = m & 1023, hh = n >> 6, d = n & 63;
                half4_t o;
                #pragma unroll
                for (int r = 0; r < 4; ++r) o[r] = (_Float16)acc[i][j][r];
                *(half4_t*)&Oh[((size_t)((b * 16 + hh) * 64 + d)) * 1024 + s] = o;
            }
        }
    } else {
        #pragma unroll
        for (int i = 0; i < 4; ++i) {
            #pragma unroll
            for (int j = 0; j < 4; ++j) {
                #pragma unroll
                for (int r = 0; r < 4; ++r) {
                    int m = M0 + wr * 64 + i * 16 + quad * 4 + r;
                    int n = N0 + wc * 64 + j * 16 + l16;
                    int b = m >> 10, s = m & 1023, hh = n >> 6, d = n & 63;
                    Oh[((size_t)((b * 16 + hh) * 1024 + s)) * 64 + d] = (_Float16)acc[i][j][r];
                }
            }
        }
    }
}

// ---------------- Output GEMM: C[4096,1024] fp32 = A @ B^T ----------------
// R7: XCD-aware 1D decode — all 8 N-blocks of one M-panel on one XCD (A=ctx16 8MB).
__global__ __launch_bounds__(256) void gemm_o_kernel(
    const _Float16* __restrict__ A,
    const _Float16* __restrict__ Bw,
    float* __restrict__ Of)
{
    const int lid = blockIdx.x;
    const int xcd = lid & 7;
    const int rr = lid >> 3;              // 0..63
    const int xb = rr & 7;
    const int yb = xcd * 8 + (rr >> 3);   // 0..63

    __shared__ __attribute__((aligned(16))) _Float16 sA[2][64][32];
    __shared__ __attribute__((aligned(16))) _Float16 sB[2][128][32];

    const int tid = threadIdx.x;
    const int wave = tid >> 6, lane = tid & 63;
    const int quad = lane >> 4, l16 = lane & 15;
    const int M0 = yb * 64, N0 = xb * 128;

    const int rl = lane >> 2;
    const int cl = (lane & 3) * 8;
    const size_t aRow  = (size_t)(M0 + wave * 16 + rl) * GK + cl;
    const size_t bRow0 = (size_t)(N0 + wave * 16 + rl) * GK + cl;
    const size_t bRow1 = bRow0 + (size_t)64 * GK;
    _Float16* ldsA[2]    = {&sA[0][wave * 16][0], &sA[1][wave * 16][0]};
    _Float16* ldsB[2][2] = {{&sB[0][wave * 16][0], &sB[0][64 + wave * 16][0]},
                            {&sB[1][wave * 16][0], &sB[1][64 + wave * 16][0]}};

    f32x4 acc[4][2] = {};

    for (int kt = 0; kt < GK / 64; ++kt) {
        const int ko = kt * 64;
        #pragma unroll
        for (int c = 0; c < 2; ++c) {
            GLD16(A + aRow + ko + c * 32, ldsA[c]);
            GLD16(Bw + bRow0 + ko + c * 32, ldsB[c][0]);
            GLD16(Bw + bRow1 + ko + c * 32, ldsB[c][1]);
        }
        __syncthreads();
        #pragma unroll
        for (int c = 0; c < 2; ++c) {
            half8 af[4], bf[2];
            #pragma unroll
            for (int i = 0; i < 4; ++i)
                af[i] = *(const half8*)&sA[c][i * 16 + l16][quad * 8];
            #pragma unroll
            for (int j = 0; j < 2; ++j)
                bf[j] = *(const half8*)&sB[c][wave * 32 + j * 16 + l16][quad * 8];
            #pragma unroll
            for (int i = 0; i < 4; ++i)
                #pragma unroll
                for (int j = 0; j < 2; ++j)
                    acc[i][j] = __builtin_amdgcn_mfma_f32_16x16x32_f16(af[i], bf[j], acc[i][j], 0, 0, 0);
        }
        __syncthreads();
    }

    #pragma unroll
    for (int i = 0; i < 4; ++i) {
        #pragma unroll
        for (int j = 0; j < 2; ++j) {
            #pragma unroll
            for (int r = 0; r < 4; ++r) {
                int m = M0 + i * 16 + quad * 4 + r;
                int n = N0 + wave * 32 + j * 16 + l16;
                Of[(size_t)m * 1024 + n] = acc[i][j][r];
            }
        }
    }
}

// ---------------- flash attention, TRANSPOSED scores (K·Q^T) ----------------
// BASELINE attn (proven 53.9us). Ledger: setprio -, defer-max/direct-Q -,
// zero-staging --, XCD swizzle 0, QBLK=128 - (occupancy halves). Unchanged.
__global__ __launch_bounds__(256) void attn_kernel(
    const _Float16* __restrict__ Q,
    const _Float16* __restrict__ K,
    const _Float16* __restrict__ VT,
    const float* __restrict__ rel_bias,   // [32][16]
    _Float16* __restrict__ ctx)           // [B*S, 1024]
{
    const int S = 1024;
    const int qt = blockIdx.x;
    const int q0 = qt * 64;
    const int h = blockIdx.y;
    const int b = blockIdx.z;
    const int bh = b * 16 + h;
    const _Float16* Qh = Q + (size_t)bh * S * 64;
    const _Float16* Kh = K + (size_t)bh * S * 64;
    const _Float16* VTh = VT + (size_t)bh * 64 * S;

    __shared__ __attribute__((aligned(16))) _Float16 sQ[64][72];
    __shared__ __attribute__((aligned(16))) _Float16 sK[64][72];
    __shared__ __attribute__((aligned(16))) _Float16 sVt[64][72];   // [d][kpos]
    __shared__ __attribute__((aligned(16))) _Float16 sP[4][16][72]; // [wave][q=l16][kpos]
    __shared__ _Float16 sBias[1088];

    const int tid = threadIdx.x;
    const int wave = tid >> 6, lane = tid & 63;
    const int quad = lane >> 4, l16 = lane & 15;

    {   // stage Q tile (once)
        int r = tid >> 3, c = (tid & 7) * 8;
        *(half8*)&sQ[r][c]      = *(const half8*)(Qh + (size_t)(q0 + r) * 64 + c);
        *(half8*)&sQ[r + 32][c] = *(const half8*)(Qh + (size_t)(q0 + r + 32) * 64 + c);
    }
    // bias window: idx = kpos - q + q0 + 63 in [0,1086]
    for (int i = tid; i < 1087; i += 256) {
        int delta = i - (q0 + 63);             // kpos - q
        int rb = (delta > 0) ? 16 : 0;
        int n = (delta < 0) ? -delta : delta;
        int bucket;
        if (n < 8) bucket = rb + n;
        else bucket = rb + 8 + (n >= 12) + (n >= 16) + (n >= 23) + (n >= 32)
                             + (n >= 46) + (n >= 64) + (n >= 91);
        sBias[i] = (_Float16)rel_bias[bucket * 16 + h];
    }
    __syncthreads();

    // q-fragment: this wave's 16 q-rows (B-operand; lane l16 = q within group)
    half8 qf0 = *(const half8*)&sQ[wave * 16 + l16][quad * 8];
    half8 qf1 = *(const half8*)&sQ[wave * 16 + l16][32 + quad * 8];

    // staging pointers (advance by constant stride per kt)
    const int sr = tid >> 3;            // 0..31
    const int sc_ = (tid & 7) * 8;      // 0..56
    const _Float16* kp0 = Kh + (size_t)sr * 64 + sc_;          // += 4096 per kt
    const _Float16* kp1 = kp0 + (size_t)32 * 64;
    const _Float16* vp0 = VTh + (size_t)sr * S + sc_;          // += 64 per kt
    const _Float16* vp1 = vp0 + (size_t)32 * S;
    _Float16* sKw0 = &sK[sr][sc_];
    _Float16* sKw1 = &sK[sr + 32][sc_];
    _Float16* sVw0 = &sVt[sr][sc_];
    _Float16* sVw1 = &sVt[sr + 32][sc_];

    // preload tile kt=0 into registers
    half8 rk0 = *(const half8*)kp0;
    half8 rk1 = *(const half8*)kp1;
    half8 rv0 = *(const half8*)vp0;
    half8 rv1 = *(const half8*)vp1;
    kp0 += 4096; kp1 += 4096; vp0 += 64; vp1 += 64;

    float m_run = -INFINITY, l_run = 0.0f;
    f32x4 acc[4] = {};   // acc[dt][r] = out^T[d = dt*16+quad*4+r][q = l16]

    for (int kt = 0; kt < 16; ++kt) {
        __syncthreads();   // prior iter's sK/sVt reads done
        *(half8*)sKw0 = rk0;
        *(half8*)sKw1 = rk1;
        *(half8*)sVw0 = rv0;
        *(half8*)sVw1 = rv1;
        __syncthreads();   // tile visible to all waves
        if (kt < 15) {     // prefetch next tile; latency hidden by compute below
            rk0 = *(const half8*)kp0;
            rk1 = *(const half8*)kp1;
            rv0 = *(const half8*)vp0;
            rv1 = *(const half8*)vp1;
            kp0 += 4096; kp1 += 4096; vp0 += 64; vp1 += 64;
        }

        // scores transposed: sc[j][r] = S[kpos = kt*64 + j*16 + quad*4 + r][q = l16]
        f32x4 sc[4] = {};
        #pragma unroll
        for (int j = 0; j < 4; ++j) {
            half8 kf0 = *(const half8*)&sK[j * 16 + l16][quad * 8];
            half8 kf1 = *(const half8*)&sK[j * 16 + l16][32 + quad * 8];
            sc[j] = __builtin_amdgcn_mfma_f32_16x16x32_f16(kf0, qf0, sc[j], 0, 0, 0);
            sc[j] = __builtin_amdgcn_mfma_f32_16x16x32_f16(kf1, qf1, sc[j], 0, 0, 0);
        }

        const int bbase = kt * 64 + quad * 4 - wave * 16 - l16 + 63;
        float ps = 0.0f;
        if (kt <= qt - 3 || kt >= qt + 3) {
            // uniform tile: one bucket -> bias is lane-uniform; fold bias & max into exp2 arg
            const float cb = (float)sBias[bbase];
            float mx = fmaxf(fmaxf(fmaxf(sc[0][0], sc[0][1]), fmaxf(sc[0][2], sc[0][3])),
                             fmaxf(fmaxf(sc[1][0], sc[1][1]), fmaxf(sc[1][2], sc[1][3])));
            mx = fmaxf(mx, fmaxf(fmaxf(fmaxf(sc[2][0], sc[2][1]), fmaxf(sc[2][2], sc[2][3])),
                                 fmaxf(fmaxf(sc[3][0], sc[3][1]), fmaxf(sc[3][2], sc[3][3]))));
            mx = fmaxf(mx, __shfl_xor(mx, 16));
            mx = fmaxf(mx, __shfl_xor(mx, 32));
            float mnew = fmaxf(m_run, mx + cb);
            float alpha = __expf(m_run - mnew);
            m_run = mnew;
            const float kk = (cb - mnew) * LOG2E;
            #pragma unroll
            for (int j = 0; j < 4; ++j) {
                half4_t pw;
                #pragma unroll
                for (int r = 0; r < 4; ++r) {
                    float p = __builtin_exp2f(__builtin_fmaf(sc[j][r], LOG2E, kk));
                    ps += p;
                    pw[r] = (_Float16)p;
                }
                *(half4_t*)&sP[wave][l16][j * 16 + quad * 4] = pw;
            }
            l_run = l_run * alpha + ps;
            #pragma unroll
            for (int dt = 0; dt < 4; ++dt) acc[dt] *= alpha;
        } else {
            // mixed tile: per-element bias (exact path)
            #pragma unroll
            for (int j = 0; j < 4; ++j)
                #pragma unroll
                for (int r = 0; r < 4; ++r)
                    sc[j][r] += (float)sBias[bbase + j * 16 + r];
            float mx = fmaxf(fmaxf(fmaxf(sc[0][0], sc[0][1]), fmaxf(sc[0][2], sc[0][3])),
                             fmaxf(fmaxf(sc[1][0], sc[1][1]), fmaxf(sc[1][2], sc[1][3])));
            mx = fmaxf(mx, fmaxf(fmaxf(fmaxf(sc[2][0], sc[2][1]), fmaxf(sc[2][2], sc[2][3])),
                                 fmaxf(fmaxf(sc[3][0], sc[3][1]), fmaxf(sc[3][2], sc[3][3]))));
            mx = fmaxf(mx, __shfl_xor(mx, 16));
            mx = fmaxf(mx, __shfl_xor(mx, 32));
            float mnew = fmaxf(m_run, mx);
            float alpha = __expf(m_run - mnew);
            m_run = mnew;
            #pragma unroll
            for (int j = 0; j < 4; ++j) {
                half4_t pw;
                #pragma unroll
                for (int r = 0; r < 4; ++r) {
                    float p = __expf(sc[j][r] - mnew);
                    ps += p;
                    pw[r] = (_Float16)p;
                }
                *(half4_t*)&sP[wave][l16][j * 16 + quad * 4] = pw;
            }
            l_run = l_run * alpha + ps;
            #pragma unroll
            for (int dt = 0; dt < 4; ++dt) acc[dt] *= alpha;
        }
        // NO barrier: sP slice is wave-private; same-wave ds_write -> ds_read is ordered.

        half8 pf0 = *(const half8*)&sP[wave][l16][quad * 8];        // B[n=q][k=kpos 0..31]
        half8 pf1 = *(const half8*)&sP[wave][l16][32 + quad * 8];   // kpos 32..63
        #pragma unroll
        for (int dt = 0; dt < 4; ++dt) {
            half8 vf0 = *(const half8*)&sVt[dt * 16 + l16][quad * 8];      // A[m=d][k=kpos]
            half8 vf1 = *(const half8*)&sVt[dt * 16 + l16][32 + quad * 8];
            acc[dt] = __builtin_amdgcn_mfma_f32_16x16x32_f16(vf0, pf0, acc[dt], 0, 0, 0);
            acc[dt] = __builtin_amdgcn_mfma_f32_16x16x32_f16(vf1, pf1, acc[dt], 0, 0, 0);
        }
    }

    // final: reduce row-sum across quads, normalize, store half4 chunks
    l_run += __shfl_xor(l_run, 16);
    l_run += __shfl_xor(l_run, 32);
    const float inv = 1.0f / l_run;
    const size_t qg = (size_t)(b * 1024 + q0 + wave * 16 + l16);
    #pragma unroll
    for (int dt = 0; dt < 4; ++dt) {
        half4_t o;
        #pragma unroll
        for (int r = 0; r < 4; ++r) o[r] = (_Float16)(acc[dt][r] * inv);
        *(half4_t*)&ctx[qg * 1024 + h * 64 + dt * 16 + quad * 4] = o;
    }
}

// ---------------- launch ----------------
extern "C" void kernel_launch(void* const* d_in, const int* in_sizes, int n_in,
                              void* d_out, int out_size, void* d_ws, size_t ws_size,
                              hipStream_t stream) {
    const float* hidden   = (const float*)d_in[0];
    const float* Wq       = (const float*)d_in[1];
    const float* Wk       = (const float*)d_in[2];
    const float* Wv       = (const float*)d_in[3];
    const float* Wo       = (const float*)d_in[4];
    const float* rel_bias = (const float*)d_in[5];
    float* out = (float*)d_out;

    _Float16* ws    = (_Float16*)d_ws;
    _Float16* h16   = ws;                     // 4M halves (fp16 hidden)
    _Float16* wq16  = ws + 4 * (size_t)MEG;
    _Float16* wk16  = ws + 5 * (size_t)MEG;
    _Float16* wv16  = ws + 6 * (size_t)MEG;
    _Float16* wo16  = ws + 7 * (size_t)MEG;
    _Float16* Qs    = ws + 8 * (size_t)MEG;   // [B,H,S,64]
    _Float16* Ks    = ws + 12 * (size_t)MEG;
    _Float16* VTs   = ws + 16 * (size_t)MEG;  // V^T [B,H,64,S] — written directly by gemm_qkv z==2
    _Float16* ctx16 = ws + 20 * (size_t)MEG;  // [B*S,1024]

    cvt_all_kernel<<<8192, 256, 0, stream>>>(hidden, Wq, Wk, Wv, Wo, ws);

    // 1D grid, XCD-aware decode (768 = 8 XCD x 12 groups x 8 N-blocks)
    gemm_qkv_kernel<<<dim3(768), 256, 0, stream>>>(
        h16, wq16, wk16, wv16, Qs, Ks, VTs);

    attn_kernel<<<dim3(16, 16, 4), 256, 0, stream>>>(Qs, Ks, VTs, rel_bias, ctx16);

    // 1D grid, XCD-aware decode (512 = 8 XCD x 8 groups x 8 N-blocks)
    gemm_o_kernel<<<dim3(512), 256, 0, stream>>>(ctx16, wo16, out);
}

// Round 9
// 187.023 us; speedup vs baseline: 1.0963x; 1.0246x over previous
//
#include <hip/hip_runtime.h>

typedef _Float16 half8 __attribute__((ext_vector_type(8)));
typedef _Float16 half4_t __attribute__((ext_vector_type(4)));
typedef float f32x4 __attribute__((ext_vector_type(4)));

#define GK 1024
#define MEG (1024 * 1024)
#define LOG2E 1.44269504088896f

// async global->LDS, 16B per lane; lptr wave-uniform, lane i's data lands at lptr + i*16
#define GLD16(gptr, lptr) \
    __builtin_amdgcn_global_load_lds((const __attribute__((address_space(1))) void*)(gptr), \
                                     (__attribute__((address_space(3))) void*)(lptr), 16, 0, 0)

// ---------------- fp32 -> fp16 convert (all 5 tensors, one launch) ----------------
__global__ void cvt_all_kernel(const float* __restrict__ hidden,
                               const float* __restrict__ Wq,
                               const float* __restrict__ Wk,
                               const float* __restrict__ Wv,
                               const float* __restrict__ Wo,
                               _Float16* __restrict__ ws) {
    int b = blockIdx.x;
    const float* src;
    _Float16* dst;
    if (b < 4096)      { src = hidden; dst = ws; }
    else if (b < 5120) { src = Wq; dst = ws + 4 * MEG; b -= 4096; }
    else if (b < 6144) { src = Wk; dst = ws + 5 * MEG; b -= 5120; }
    else if (b < 7168) { src = Wv; dst = ws + 6 * MEG; b -= 6144; }
    else               { src = Wo; dst = ws + 7 * MEG; b -= 7168; }
    int i = (b * 256 + threadIdx.x) * 4;
    f32x4 v = *(const f32x4*)(src + i);
    half4_t h;
    h[0] = (_Float16)v[0]; h[1] = (_Float16)v[1];
    h[2] = (_Float16)v[2]; h[3] = (_Float16)v[3];
    *(half4_t*)(dst + i) = h;
}

// ---------------- QKV GEMM: C[4096,1024] = A @ B^T, z picks (Wq,Q)/(Wk,K)/(Wv,V) ----------------
// XCD-aware 1D grid decode; z==2 (V) writes transposed [bh][d][s] directly.
__global__ __launch_bounds__(256) void gemm_qkv_kernel(
    const _Float16* __restrict__ A,
    const _Float16* __restrict__ B0,
    const _Float16* __restrict__ B1,
    const _Float16* __restrict__ B2,
    _Float16* __restrict__ O0,
    _Float16* __restrict__ O1,
    _Float16* __restrict__ O2)
{
    // decode: lid = xcd + 8*(xb + 8*gidx), gg = xcd*12 + gidx in [0,96), y=gg&31, z=gg>>5
    const int lid = blockIdx.x;
    const int xcd = lid & 7;
    const int rr = lid >> 3;              // 0..95
    const int xb = rr & 7;                // N-block
    const int gg = xcd * 12 + (rr >> 3);  // 0..95
    const int yb = gg & 31;               // M-block
    const int z  = gg >> 5;               // 0..2
    const _Float16* Bw = (z == 0) ? B0 : ((z == 1) ? B1 : B2);
    _Float16* Oh = (z == 0) ? O0 : ((z == 1) ? O1 : O2);

    __shared__ __attribute__((aligned(16))) _Float16 sA[2][128][32];
    __shared__ __attribute__((aligned(16))) _Float16 sB[2][128][32];

    const int tid = threadIdx.x;
    const int wave = tid >> 6, lane = tid & 63;
    const int quad = lane >> 4, l16 = lane & 15;
    const int wr = wave >> 1, wc = wave & 1;
    const int M0 = yb * 128, N0 = xb * 128;

    const int rl = lane >> 2;
    const int cl = (lane & 3) * 8;   // halfs within chunk
    const size_t aRow0 = (size_t)(M0 + wave * 16 + rl) * GK + cl;
    const size_t aRow1 = aRow0 + (size_t)64 * GK;
    const size_t bRow0 = (size_t)(N0 + wave * 16 + rl) * GK + cl;
    const size_t bRow1 = bRow0 + (size_t)64 * GK;
    _Float16* ldsA[2][2] = {{&sA[0][wave * 16][0], &sA[0][64 + wave * 16][0]},
                            {&sA[1][wave * 16][0], &sA[1][64 + wave * 16][0]}};
    _Float16* ldsB[2][2] = {{&sB[0][wave * 16][0], &sB[0][64 + wave * 16][0]},
                            {&sB[1][wave * 16][0], &sB[1][64 + wave * 16][0]}};

    f32x4 acc[4][4] = {};

    for (int kt = 0; kt < GK / 64; ++kt) {
        const int ko = kt * 64;
        #pragma unroll
        for (int c = 0; c < 2; ++c) {
            GLD16(A + aRow0 + ko + c * 32, ldsA[c][0]);
            GLD16(A + aRow1 + ko + c * 32, ldsA[c][1]);
            GLD16(Bw + bRow0 + ko + c * 32, ldsB[c][0]);
            GLD16(Bw + bRow1 + ko + c * 32, ldsB[c][1]);
        }
        __syncthreads();
        #pragma unroll
        for (int c = 0; c < 2; ++c) {
            half8 af[4], bf[4];
            #pragma unroll
            for (int i = 0; i < 4; ++i)
                af[i] = *(const half8*)&sA[c][wr * 64 + i * 16 + l16][quad * 8];
            #pragma unroll
            for (int j = 0; j < 4; ++j)
                bf[j] = *(const half8*)&sB[c][wc * 64 + j * 16 + l16][quad * 8];
            #pragma unroll
            for (int i = 0; i < 4; ++i)
                #pragma unroll
                for (int j = 0; j < 4; ++j)
                    acc[i][j] = __builtin_amdgcn_mfma_f32_16x16x32_f16(af[i], bf[j], acc[i][j], 0, 0, 0);
        }
        __syncthreads();
    }

    if (z == 2) {
        // V: store transposed [bh][d][s] (VT). Along r, s varies by 1 -> half4 store.
        #pragma unroll
        for (int i = 0; i < 4; ++i) {
            #pragma unroll
            for (int j = 0; j < 4; ++j) {
                int m = M0 + wr * 64 + i * 16 + quad * 4;        // r=0 base (s-dim)
                int n = N0 + wc * 64 + j * 16 + l16;
                int b = m >> 10, s = m & 1023, hh = n >> 6, d = n & 63;
                half4_t o;
                #pragma unroll
                for (int r = 0; r < 4; ++r) o[r] = (_Float16)acc[i][j][r];
                *(half4_t*)&Oh[((size_t)((b * 16 + hh) * 64 + d)) * 1024 + s] = o;
            }
        }
    } else {
        #pragma unroll
        for (int i = 0; i < 4; ++i) {
            #pragma unroll
            for (int j = 0; j < 4; ++j) {
                #pragma unroll
                for (int r = 0; r < 4; ++r) {
                    int m = M0 + wr * 64 + i * 16 + quad * 4 + r;
                    int n = N0 + wc * 64 + j * 16 + l16;
                    int b = m >> 10, s = m & 1023, hh = n >> 6, d = n & 63;
                    Oh[((size_t)((b * 16 + hh) * 1024 + s)) * 64 + d] = (_Float16)acc[i][j][r];
                }
            }
        }
    }
}

// ---------------- Output GEMM: C[4096,1024] fp32 = A @ B^T ----------------
__global__ __launch_bounds__(256) void gemm_o_kernel(
    const _Float16* __restrict__ A,
    const _Float16* __restrict__ Bw,
    float* __restrict__ Of)
{
    const int lid = blockIdx.x;
    const int xcd = lid & 7;
    const int rr = lid >> 3;              // 0..63
    const int xb = rr & 7;
    const int yb = xcd * 8 + (rr >> 3);   // 0..63

    __shared__ __attribute__((aligned(16))) _Float16 sA[2][64][32];
    __shared__ __attribute__((aligned(16))) _Float16 sB[2][128][32];

    const int tid = threadIdx.x;
    const int wave = tid >> 6, lane = tid & 63;
    const int quad = lane >> 4, l16 = lane & 15;
    const int M0 = yb * 64, N0 = xb * 128;

    const int rl = lane >> 2;
    const int cl = (lane & 3) * 8;
    const size_t aRow  = (size_t)(M0 + wave * 16 + rl) * GK + cl;
    const size_t bRow0 = (size_t)(N0 + wave * 16 + rl) * GK + cl;
    const size_t bRow1 = bRow0 + (size_t)64 * GK;
    _Float16* ldsA[2]    = {&sA[0][wave * 16][0], &sA[1][wave * 16][0]};
    _Float16* ldsB[2][2] = {{&sB[0][wave * 16][0], &sB[0][64 + wave * 16][0]},
                            {&sB[1][wave * 16][0], &sB[1][64 + wave * 16][0]}};

    f32x4 acc[4][2] = {};

    for (int kt = 0; kt < GK / 64; ++kt) {
        const int ko = kt * 64;
        #pragma unroll
        for (int c = 0; c < 2; ++c) {
            GLD16(A + aRow + ko + c * 32, ldsA[c]);
            GLD16(Bw + bRow0 + ko + c * 32, ldsB[c][0]);
            GLD16(Bw + bRow1 + ko + c * 32, ldsB[c][1]);
        }
        __syncthreads();
        #pragma unroll
        for (int c = 0; c < 2; ++c) {
            half8 af[4], bf[2];
            #pragma unroll
            for (int i = 0; i < 4; ++i)
                af[i] = *(const half8*)&sA[c][i * 16 + l16][quad * 8];
            #pragma unroll
            for (int j = 0; j < 2; ++j)
                bf[j] = *(const half8*)&sB[c][wave * 32 + j * 16 + l16][quad * 8];
            #pragma unroll
            for (int i = 0; i < 4; ++i)
                #pragma unroll
                for (int j = 0; j < 2; ++j)
                    acc[i][j] = __builtin_amdgcn_mfma_f32_16x16x32_f16(af[i], bf[j], acc[i][j], 0, 0, 0);
        }
        __syncthreads();
    }

    #pragma unroll
    for (int i = 0; i < 4; ++i) {
        #pragma unroll
        for (int j = 0; j < 2; ++j) {
            #pragma unroll
            for (int r = 0; r < 4; ++r) {
                int m = M0 + i * 16 + quad * 4 + r;
                int n = N0 + wave * 32 + j * 16 + l16;
                Of[(size_t)m * 1024 + n] = acc[i][j][r];
            }
        }
    }
}

// ---------------- flash attention, TRANSPOSED scores (K·Q^T), 8-wave QBLK=128 ----------------
// R9: per-WAVE inner loop identical to the proven 53.9us baseline (16 q-rows/wave);
// block groups 8 waves (512 thr) over 128 q-rows. vs R6's failure (4w x 2blk = 8
// waves/CU): here 2 blocks/CU x 8 waves = 16 waves/CU, SAME as baseline. Per unit
// work: staging instrs halve (1 K + 1 V half8 per thread), barrier-iters halve,
// K/V HBM re-reads halve. LDS 57.5KB -> exactly 2 blocks/CU.
__global__ __launch_bounds__(512) void attn_kernel(
    const _Float16* __restrict__ Q,
    const _Float16* __restrict__ K,
    const _Float16* __restrict__ VT,
    const float* __restrict__ rel_bias,   // [32][16]
    _Float16* __restrict__ ctx)           // [B*S, 1024]
{
    const int S = 1024;
    const int qt = blockIdx.x;            // 0..7, QBLK=128
    const int q0 = qt * 128;
    const int h = blockIdx.y;
    const int b = blockIdx.z;
    const int bh = b * 16 + h;
    const _Float16* Qh = Q + (size_t)bh * S * 64;
    const _Float16* Kh = K + (size_t)bh * S * 64;
    const _Float16* VTh = VT + (size_t)bh * 64 * S;

    __shared__ __attribute__((aligned(16))) _Float16 sQ[128][72];
    __shared__ __attribute__((aligned(16))) _Float16 sK[64][72];
    __shared__ __attribute__((aligned(16))) _Float16 sVt[64][72];   // [d][kpos]
    __shared__ __attribute__((aligned(16))) _Float16 sP[8][16][72]; // [wave][q=l16][kpos]
    __shared__ _Float16 sBias[1152];

    const int tid = threadIdx.x;
    const int wave = tid >> 6, lane = tid & 63;
    const int quad = lane >> 4, l16 = lane & 15;

    {   // stage Q tile (once): 2 rows per thread
        int r = tid >> 3, c = (tid & 7) * 8;   // r 0..63
        *(half8*)&sQ[r][c]      = *(const half8*)(Qh + (size_t)(q0 + r) * 64 + c);
        *(half8*)&sQ[r + 64][c] = *(const half8*)(Qh + (size_t)(q0 + r + 64) * 64 + c);
    }
    // bias window: idx = kpos - q + q0 + 127 in [0,1150]
    for (int i = tid; i < 1151; i += 512) {
        int delta = i - (q0 + 127);            // kpos - q
        int rb = (delta > 0) ? 16 : 0;
        int n = (delta < 0) ? -delta : delta;
        int bucket;
        if (n < 8) bucket = rb + n;
        else bucket = rb + 8 + (n >= 12) + (n >= 16) + (n >= 23) + (n >= 32)
                             + (n >= 46) + (n >= 64) + (n >= 91);
        sBias[i] = (_Float16)rel_bias[bucket * 16 + h];
    }
    __syncthreads();

    // q-fragment: this wave's 16 q-rows (B-operand; lane l16 = q within group)
    half8 qf0 = *(const half8*)&sQ[wave * 16 + l16][quad * 8];
    half8 qf1 = *(const half8*)&sQ[wave * 16 + l16][32 + quad * 8];

    // staging: 512 threads cover the 64x64 K tile and V tile with ONE half8 each
    const int sr = tid >> 3;            // 0..63
    const int sc_ = (tid & 7) * 8;      // 0..56
    const _Float16* kp = Kh + (size_t)sr * 64 + sc_;           // += 4096 per kt
    const _Float16* vp = VTh + (size_t)sr * S + sc_;           // += 64 per kt
    _Float16* sKw = &sK[sr][sc_];
    _Float16* sVw = &sVt[sr][sc_];

    // preload tile kt=0 into registers
    half8 rk = *(const half8*)kp;
    half8 rv = *(const half8*)vp;
    kp += 4096; vp += 64;

    float m_run = -INFINITY, l_run = 0.0f;
    f32x4 acc[4] = {};   // acc[dt][r] = out^T[d = dt*16+quad*4+r][q = l16]

    for (int kt = 0; kt < 16; ++kt) {
        __syncthreads();   // prior iter's sK/sVt reads done
        *(half8*)sKw = rk;
        *(half8*)sVw = rv;
        __syncthreads();   // tile visible to all waves
        if (kt < 15) {     // prefetch next tile; latency hidden by compute below
            rk = *(const half8*)kp;
            rv = *(const half8*)vp;
            kp += 4096; vp += 64;
        }

        // scores transposed: sc[j][r] = S[kpos = kt*64 + j*16 + quad*4 + r][q = l16]
        f32x4 sc[4] = {};
        #pragma unroll
        for (int j = 0; j < 4; ++j) {
            half8 kf0 = *(const half8*)&sK[j * 16 + l16][quad * 8];
            half8 kf1 = *(const half8*)&sK[j * 16 + l16][32 + quad * 8];
            sc[j] = __builtin_amdgcn_mfma_f32_16x16x32_f16(kf0, qf0, sc[j], 0, 0, 0);
            sc[j] = __builtin_amdgcn_mfma_f32_16x16x32_f16(kf1, qf1, sc[j], 0, 0, 0);
        }

        const int bbase = kt * 64 + quad * 4 - wave * 16 - l16 + 127;
        float ps = 0.0f;
        if (kt <= 2 * qt - 3 || kt >= 2 * qt + 4) {
            // uniform tile: one bucket -> bias lane-uniform; fold bias & max into exp2 arg
            const float cb = (float)sBias[bbase];
            float mx = fmaxf(fmaxf(fmaxf(sc[0][0], sc[0][1]), fmaxf(sc[0][2], sc[0][3])),
                             fmaxf(fmaxf(sc[1][0], sc[1][1]), fmaxf(sc[1][2], sc[1][3])));
            mx = fmaxf(mx, fmaxf(fmaxf(fmaxf(sc[2][0], sc[2][1]), fmaxf(sc[2][2], sc[2][3])),
                                 fmaxf(fmaxf(sc[3][0], sc[3][1]), fmaxf(sc[3][2], sc[3][3]))));
            mx = fmaxf(mx, __shfl_xor(mx, 16));
            mx = fmaxf(mx, __shfl_xor(mx, 32));
            float mnew = fmaxf(m_run, mx + cb);
            float alpha = __expf(m_run - mnew);
            m_run = mnew;
            const float kk = (cb - mnew) * LOG2E;
            #pragma unroll
            for (int j = 0; j < 4; ++j) {
                half4_t pw;
                #pragma unroll
                for (int r = 0; r < 4; ++r) {
                    float p = __builtin_exp2f(__builtin_fmaf(sc[j][r], LOG2E, kk));
                    ps += p;
                    pw[r] = (_Float16)p;
                }
                *(half4_t*)&sP[wave][l16][j * 16 + quad * 4] = pw;
            }
            l_run = l_run * alpha + ps;
            #pragma unroll
            for (int dt = 0; dt < 4; ++dt) acc[dt] *= alpha;
        } else {
            // mixed tile: per-element bias (exact path)
            #pragma unroll
            for (int j = 0; j < 4; ++j)
                #pragma unroll
                for (int r = 0; r < 4; ++r)
                    sc[j][r] += (float)sBias[bbase + j * 16 + r];
            float mx = fmaxf(fmaxf(fmaxf(sc[0][0], sc[0][1]), fmaxf(sc[0][2], sc[0][3])),
                             fmaxf(fmaxf(sc[1][0], sc[1][1]), fmaxf(sc[1][2], sc[1][3])));
            mx = fmaxf(mx, fmaxf(fmaxf(fmaxf(sc[2][0], sc[2][1]), fmaxf(sc[2][2], sc[2][3])),
                                 fmaxf(fmaxf(sc[3][0], sc[3][1]), fmaxf(sc[3][2], sc[3][3]))));
            mx = fmaxf(mx, __shfl_xor(mx, 16));
            mx = fmaxf(mx, __shfl_xor(mx, 32));
            float mnew = fmaxf(m_run, mx);
            float alpha = __expf(m_run - mnew);
            m_run = mnew;
            #pragma unroll
            for (int j = 0; j < 4; ++j) {
                half4_t pw;
                #pragma unroll
                for (int r = 0; r < 4; ++r) {
                    float p = __expf(sc[j][r] - mnew);
                    ps += p;
                    pw[r] = (_Float16)p;
                }
                *(half4_t*)&sP[wave][l16][j * 16 + quad * 4] = pw;
            }
            l_run = l_run * alpha + ps;
            #pragma unroll
            for (int dt = 0; dt < 4; ++dt) acc[dt] *= alpha;
        }
        // NO barrier: sP slice is wave-private; same-wave ds_write -> ds_read is ordered.

        half8 pf0 = *(const half8*)&sP[wave][l16][quad * 8];        // B[n=q][k=kpos 0..31]
        half8 pf1 = *(const half8*)&sP[wave][l16][32 + quad * 8];   // kpos 32..63
        #pragma unroll
        for (int dt = 0; dt < 4; ++dt) {
            half8 vf0 = *(const half8*)&sVt[dt * 16 + l16][quad * 8];      // A[m=d][k=kpos]
            half8 vf1 = *(const half8*)&sVt[dt * 16 + l16][32 + quad * 8];
            acc[dt] = __builtin_amdgcn_mfma_f32_16x16x32_f16(vf0, pf0, acc[dt], 0, 0, 0);
            acc[dt] = __builtin_amdgcn_mfma_f32_16x16x32_f16(vf1, pf1, acc[dt], 0, 0, 0);
        }
    }

    // final: reduce row-sum across quads, normalize, store half4 chunks
    l_run += __shfl_xor(l_run, 16);
    l_run += __shfl_xor(l_run, 32);
    const float inv = 1.0f / l_run;
    const size_t qg = (size_t)(b * 1024 + q0 + wave * 16 + l16);
    #pragma unroll
    for (int dt = 0; dt < 4; ++dt) {
        half4_t o;
        #pragma unroll
        for (int r = 0; r < 4; ++r) o[r] = (_Float16)(acc[dt][r] * inv);
        *(half4_t*)&ctx[qg * 1024 + h * 64 + dt * 16 + quad * 4] = o;
    }
}

// ---------------- launch ----------------
extern "C" void kernel_launch(void* const* d_in, const int* in_sizes, int n_in,
                              void* d_out, int out_size, void* d_ws, size_t ws_size,
                              hipStream_t stream) {
    const float* hidden   = (const float*)d_in[0];
    const float* Wq       = (const float*)d_in[1];
    const float* Wk       = (const float*)d_in[2];
    const float* Wv       = (const float*)d_in[3];
    const float* Wo       = (const float*)d_in[4];
    const float* rel_bias = (const float*)d_in[5];
    float* out = (float*)d_out;

    _Float16* ws    = (_Float16*)d_ws;
    _Float16* h16   = ws;                     // 4M halves (fp16 hidden)
    _Float16* wq16  = ws + 4 * (size_t)MEG;
    _Float16* wk16  = ws + 5 * (size_t)MEG;
    _Float16* wv16  = ws + 6 * (size_t)MEG;
    _Float16* wo16  = ws + 7 * (size_t)MEG;
    _Float16* Qs    = ws + 8 * (size_t)MEG;   // [B,H,S,64]
    _Float16* Ks    = ws + 12 * (size_t)MEG;
    _Float16* VTs   = ws + 16 * (size_t)MEG;  // V^T [B,H,64,S] — written directly by gemm_qkv z==2
    _Float16* ctx16 = ws + 20 * (size_t)MEG;  // [B*S,1024]

    cvt_all_kernel<<<8192, 256, 0, stream>>>(hidden, Wq, Wk, Wv, Wo, ws);

    // 1D grid, XCD-aware decode (768 = 8 XCD x 12 groups x 8 N-blocks)
    gemm_qkv_kernel<<<dim3(768), 256, 0, stream>>>(
        h16, wq16, wk16, wv16, Qs, Ks, VTs);

    // 8-wave QBLK=128: 8 q-tiles x 16 heads x 4 batch = 512 blocks = 2/CU
    attn_kernel<<<dim3(8, 16, 4), 512, 0, stream>>>(Qs, Ks, VTs, rel_bias, ctx16);

    // 1D grid, XCD-aware decode (512 = 8 XCD x 8 groups x 8 N-blocks)
    gemm_o_kernel<<<dim3(512), 256, 0, stream>>>(ctx16, wo16, out);
}